// Round 1
// 709.574 us; speedup vs baseline: 1.5161x; 1.5161x over previous
//
#include <hip/hip_runtime.h>
#include <hip/hip_bf16.h>

// Problem constants
#define B_ROWS 2048
#define UDIM   10000
#define XDIM   20000
#define KTOT   50000   // 2*XDIM + UDIM
#define NF     128
#define KCHUNK 1280    // split-K chunk (multiple of 32)

typedef __attribute__((ext_vector_type(8))) short bf16x8;
typedef __attribute__((ext_vector_type(8))) unsigned short us8;
typedef __attribute__((ext_vector_type(4))) float f32x4;

__device__ inline void atomic_add_f32(float* p, float v) {
#if defined(__AMDGCN__)
    unsafeAtomicAdd(p, v);
#else
    atomicAdd(p, v);
#endif
}

__device__ inline unsigned short f2bf(float x) {
    union { float f; unsigned u; } a; a.f = x;
    unsigned r = a.u + 0x7FFF + ((a.u >> 16) & 1);   // round-to-nearest-even
    return (unsigned short)(r >> 16);
}

// ---------------------------------------------------------------------------
// Prep: Bt[n][k] bf16 (rows 0..127 = V^T, 128..255 = T^T) AND the combined
// Gram vector cvec[k] = vv[k] + 2*tt[k] + 2*vt[k]  (fp32 exact).
// Reads V,T exactly once.
__global__ __launch_bounds__(256) void prep_kernel(
    const float* __restrict__ V, const float* __restrict__ T,
    unsigned short* __restrict__ Bt, float* __restrict__ cvec)
{
    __shared__ unsigned short lv[NF][68];   // [j][k], pad 68 (136 B rows)
    __shared__ unsigned short lt[NF][68];
    const int k0 = blockIdx.x * 64;
    const int rows = min(64, KTOT - k0);

    for (int idx = threadIdx.x; idx < rows * 32; idx += 256) {
        int r  = idx >> 5;
        int j4 = (idx & 31) * 4;
        float4 v = *(const float4*)&V[(size_t)(k0 + r) * NF + j4];
        float4 t = *(const float4*)&T[(size_t)(k0 + r) * NF + j4];
        lv[j4 + 0][r] = f2bf(v.x); lv[j4 + 1][r] = f2bf(v.y);
        lv[j4 + 2][r] = f2bf(v.z); lv[j4 + 3][r] = f2bf(v.w);
        lt[j4 + 0][r] = f2bf(t.x); lt[j4 + 1][r] = f2bf(t.y);
        lt[j4 + 2][r] = f2bf(t.z); lt[j4 + 3][r] = f2bf(t.w);
        // combined gram diag partial: v*v + 2*t*t + 2*v*t
        float cc = v.x*v.x + 2.f*(t.x*t.x + v.x*t.x)
                 + v.y*v.y + 2.f*(t.y*t.y + v.y*t.y)
                 + v.z*v.z + 2.f*(t.z*t.z + v.z*t.z)
                 + v.w*v.w + 2.f*(t.w*t.w + v.w*t.w);
        #pragma unroll
        for (int off = 16; off > 0; off >>= 1)
            cc += __shfl_down(cc, off, 32);
        if ((threadIdx.x & 31) == 0) cvec[k0 + r] = cc;
    }
    __syncthreads();

    const int mat = threadIdx.x >> 7;     // 0 = V, 1 = T
    const int j   = threadIdx.x & 127;
    const unsigned short* src = mat ? &lt[j][0] : &lv[j][0];
    unsigned short* dst = Bt + (size_t)(mat * NF + j) * KTOT + k0;
    for (int c = 0; c < rows; c += 4)
        *(ushort4*)&dst[c] = *(const ushort4*)&src[c];
}

// ---------------------------------------------------------------------------
// Fused bf16 MFMA GEMM over all four sources (z-decoded) with register
// prefetch pipeline + fused per-row scalar dot products (fp32, pre-convert).
// Block tile 128x128, 4 waves (2x2), wave tile 64x64 via 16 mfma_16x16x32.
// Split-K over z-chunks, atomic fp32 accumulate into G (256 cols) and S.
__global__ __launch_bounds__(256) void gemm_fused_kernel(
    const float* __restrict__ u, const float* __restrict__ xprev,
    const float* __restrict__ xpos, const float* __restrict__ xneg,
    const unsigned short* __restrict__ Bt,
    const float* __restrict__ cvec, const float* __restrict__ W,
    float* __restrict__ G, float* __restrict__ S)
{
    __shared__ unsigned short As[128][40];   // [m][k], 80 B rows (16B-aligned)
    __shared__ unsigned short Bs[128][40];   // [n][k]

    const int tid  = threadIdx.x;
    const int lane = tid & 63;
    const int wave = tid >> 6;
    const int wm = (wave >> 1) * 64;
    const int wn = (wave & 1) * 64;
    const int fm = lane & 15;
    const int fq = lane >> 4;

    const int m0 = blockIdx.x * 128;
    const int n0 = blockIdx.y * 128;

    // decode source + chunk:  z = [0,8) u | [8,24) xprev | [24,40) xpos | [40,56) xneg
    const int zz = blockIdx.z;
    const float* A; int Ksrc, roff, gofs, sofs, chunk;
    if (zz < 8)       { A = u;     Ksrc = UDIM; roff = 0;           gofs = 0; sofs = 0; chunk = zz;      }
    else if (zz < 24) { A = xprev; Ksrc = XDIM; roff = UDIM;        gofs = 0; sofs = 1; chunk = zz - 8;  }
    else if (zz < 40) { A = xpos;  Ksrc = XDIM; roff = UDIM + XDIM; gofs = 1; sofs = 2; chunk = zz - 24; }
    else              { A = xneg;  Ksrc = XDIM; roff = UDIM + XDIM; gofs = 2; sofs = 3; chunk = zz - 40; }
    const int k0 = chunk * KCHUNK;
    const int k1 = min(k0 + KCHUNK, Ksrc);
    const bool doS = (blockIdx.y == 0);      // scalars depend only on A: compute once

    // staging geometry: each thread owns row am, 16 contiguous k's (half)
    const int am   = tid >> 1;
    const int half = tid & 1;
    const float* Arow = A + (size_t)(m0 + am) * Ksrc;
    const unsigned short* Brow = Bt + (size_t)(n0 + am) * KTOT + roff;
    const float* crow = cvec + roff;
    const float* wrow = W + roff;

    f32x4 acc[4][4];
    #pragma unroll
    for (int i = 0; i < 4; ++i)
        #pragma unroll
        for (int j = 0; j < 4; ++j)
            acc[i][j] = (f32x4){0.f, 0.f, 0.f, 0.f};

    float4 apf[4];
    us8 bpf0, bpf1;
    auto stage_load = [&](int kk) {
        const int base = kk + half * 16;
        if (base < k1) {                      // k1 is a multiple of 16 -> full vec valid
            const float4* ap = (const float4*)(Arow + base);
            apf[0] = ap[0]; apf[1] = ap[1]; apf[2] = ap[2]; apf[3] = ap[3];
            const us8* bp = (const us8*)(Brow + base);
            bpf0 = bp[0]; bpf1 = bp[1];
        } else {
            apf[0] = apf[1] = apf[2] = apf[3] = make_float4(0.f, 0.f, 0.f, 0.f);
            bpf0 = (us8){0,0,0,0,0,0,0,0};
            bpf1 = (us8){0,0,0,0,0,0,0,0};
        }
    };

    float sc = 0.f, sw = 0.f, ss = 0.f;      // a@c, a@W, sum(a)  (fp32 exact)

    stage_load(k0);                          // prologue
    #pragma unroll 1
    for (int k = k0; k < k1; k += 32) {
        const int base = k + half * 16;
        // ---- convert + LDS store (consumes prefetch regs) ----
        us8 lo, hi;
        lo[0] = f2bf(apf[0].x); lo[1] = f2bf(apf[0].y);
        lo[2] = f2bf(apf[0].z); lo[3] = f2bf(apf[0].w);
        lo[4] = f2bf(apf[1].x); lo[5] = f2bf(apf[1].y);
        lo[6] = f2bf(apf[1].z); lo[7] = f2bf(apf[1].w);
        hi[0] = f2bf(apf[2].x); hi[1] = f2bf(apf[2].y);
        hi[2] = f2bf(apf[2].z); hi[3] = f2bf(apf[2].w);
        hi[4] = f2bf(apf[3].x); hi[5] = f2bf(apf[3].y);
        hi[6] = f2bf(apf[3].z); hi[7] = f2bf(apf[3].w);
        *(us8*)&As[am][half * 16 + 0] = lo;
        *(us8*)&As[am][half * 16 + 8] = hi;
        *(us8*)&Bs[am][half * 16 + 0] = bpf0;
        *(us8*)&Bs[am][half * 16 + 8] = bpf1;

        // ---- fused row scalars from the fp32 values (L2-hot c/W loads) ----
        if (doS && base < k1) {
            const float4* c4 = (const float4*)(crow + base);
            const float4* w4 = (const float4*)(wrow + base);
            #pragma unroll
            for (int q = 0; q < 4; ++q) {
                float4 a = apf[q], c = c4[q], w = w4[q];
                sc += a.x * c.x + a.y * c.y + a.z * c.z + a.w * c.w;
                sw += a.x * w.x + a.y * w.y + a.z * w.z + a.w * w.w;
                ss += a.x + a.y + a.z + a.w;
            }
        }
        __syncthreads();

        // ---- issue next tile's global loads: overlap with MFMA section ----
        if (k + 32 < k1) stage_load(k + 32);

        bf16x8 af[4], bfr[4];
        #pragma unroll
        for (int i = 0; i < 4; ++i)
            af[i] = *(const bf16x8*)&As[wm + i * 16 + fm][fq * 8];
        #pragma unroll
        for (int j = 0; j < 4; ++j)
            bfr[j] = *(const bf16x8*)&Bs[wn + j * 16 + fm][fq * 8];
        #pragma unroll
        for (int i = 0; i < 4; ++i)
            #pragma unroll
            for (int j = 0; j < 4; ++j)
                acc[i][j] = __builtin_amdgcn_mfma_f32_16x16x32_bf16(
                    af[i], bfr[j], acc[i][j], 0, 0, 0);
        __syncthreads();
    }

    // ---- scalar reduce (2 threads per row) + atomic into S ----
    if (doS) {
        sc += __shfl_xor(sc, 1, 64);
        sw += __shfl_xor(sw, 1, 64);
        ss += __shfl_xor(ss, 1, 64);
        if (half == 0) {
            float* Sp = S + (size_t)sofs * B_ROWS * 3 + (size_t)(m0 + am) * 3;
            atomic_add_f32(&Sp[0], sc);
            atomic_add_f32(&Sp[1], sw);
            atomic_add_f32(&Sp[2], ss);
        }
    }

    // ---- atomic accumulate G: C/D layout col=lane&15, row=(lane>>4)*4+r ----
    float* Gseg = G + (size_t)gofs * B_ROWS * 256;
    #pragma unroll
    for (int i = 0; i < 4; ++i) {
        #pragma unroll
        for (int j = 0; j < 4; ++j) {
            const int col = n0 + wn + j * 16 + fm;
            #pragma unroll
            for (int r = 0; r < 4; ++r) {
                const int row = m0 + wm + i * 16 + fq * 4 + r;
                atomic_add_f32(&Gseg[(size_t)row * 256 + col], acc[i][j][r]);
            }
        }
    }
}

// ---------------------------------------------------------------------------
// Final combine: one wave per batch row.
// S[src][b] = {a@c, a@W, sum(a)},  c = vv + 2tt + 2vt
// quad = 0.5*zs*zc - sum(vx^2) - sum(tx*vx) - 0.5*sum(tx^2)
__global__ __launch_bounds__(256) void epilogue_kernel(
    const float* __restrict__ G, const float* __restrict__ S,
    const float* __restrict__ bias, float* __restrict__ out)
{
    const int wave = threadIdx.x >> 6, lane = threadIdx.x & 63;
    const int b = blockIdx.x * 4 + wave;
    const float* Gs = G + (size_t)b * 256;
    const float* Gp = G + (size_t)B_ROWS * 256 + (size_t)b * 256;
    const float* Gn = G + (size_t)2 * B_ROWS * 256 + (size_t)b * 256;

    float t5p = 0.f, t6p = 0.f, dgp = 0.f, t5n = 0.f, t6n = 0.f, dgn = 0.f;
    #pragma unroll
    for (int jj = 0; jj < 2; ++jj) {
        int j = lane + jj * 64;
        float vxs = Gs[j],       txs = Gs[128 + j];
        float vxp = vxs + Gp[j], txp = txs + Gp[128 + j];
        float vxn = vxs + Gn[j], txn = txs + Gn[128 + j];
        t5p += vxp * vxp; t6p += txp * vxp; dgp += txp * txp;
        t5n += vxn * vxn; t6n += txn * vxn; dgn += txn * txn;
    }
    #pragma unroll
    for (int off = 32; off > 0; off >>= 1) {
        t5p += __shfl_down(t5p, off, 64); t6p += __shfl_down(t6p, off, 64);
        dgp += __shfl_down(dgp, off, 64); t5n += __shfl_down(t5n, off, 64);
        t6n += __shfl_down(t6n, off, 64); dgn += __shfl_down(dgn, off, 64);
    }
    if (lane == 0) {
        const float* Su = S + (size_t)b * 3;
        const float* Sp = S + (size_t)B_ROWS * 3 + (size_t)b * 3;
        const float* Sx = S + (size_t)2 * B_ROWS * 3 + (size_t)b * 3;
        const float* Sn = S + (size_t)3 * B_ROWS * 3 + (size_t)b * 3;
        const float bv = bias[0];

        float zc_p = Su[0] + Sp[0] + Sx[0];
        float zs_p = Su[2] + Sp[2] + Sx[2];
        float zc_n = Su[0] + Sp[0] + Sn[0];
        float zs_n = Su[2] + Sp[2] + Sn[2];
        float lin_n = Su[1] + Sp[1] + Sn[1] + bv;   // faithful: neg linear for both

        float qp = 0.5f * zs_p * zc_p - t5p - t6p - 0.5f * dgp;
        float qn = 0.5f * zs_n * zc_n - t5n - t6n - 0.5f * dgn;

        out[b]          = lin_n + qp;
        out[B_ROWS + b] = lin_n + qn;
    }
}

// ---------------------------------------------------------------------------
extern "C" void kernel_launch(void* const* d_in, const int* in_sizes, int n_in,
                              void* d_out, int out_size, void* d_ws, size_t ws_size,
                              hipStream_t stream) {
    const float* u     = (const float*)d_in[0];
    const float* xprev = (const float*)d_in[1];
    const float* xpos  = (const float*)d_in[2];
    const float* xneg  = (const float*)d_in[3];
    const float* V     = (const float*)d_in[4];
    const float* T     = (const float*)d_in[5];
    const float* W     = (const float*)d_in[6];
    const float* bias  = (const float*)d_in[7];
    float* out = (float*)d_out;

    // Workspace layout
    unsigned short* Bt = (unsigned short*)d_ws;            // 256*KTOT bf16 = 25.6 MB
    float* cvec = (float*)(Bt + (size_t)256 * KTOT);       // KTOT floats
    float* G    = cvec + KTOT;                             // 3 * B_ROWS * 256
    float* S    = G + (size_t)3 * B_ROWS * 256;            // 4 * B_ROWS * 3

    hipMemsetAsync(G, 0, (size_t)3 * B_ROWS * 256 * sizeof(float), stream);
    hipMemsetAsync(S, 0, (size_t)4 * B_ROWS * 3 * sizeof(float), stream);

    prep_kernel<<<(KTOT + 63) / 64, 256, 0, stream>>>(V, T, Bt, cvec);

    // One fused GEMM dispatch: z = 8 (u) + 16 (xprev) + 16 (xpos) + 16 (xneg)
    gemm_fused_kernel<<<dim3(16, 2, 56), 256, 0, stream>>>(
        u, xprev, xpos, xneg, Bt, cvec, W, G, S);

    epilogue_kernel<<<B_ROWS / 4, 256, 0, stream>>>(G, S, bias, out);
}